// Round 2
// baseline (943.319 us; speedup 1.0000x reference)
//
#include <hip/hip_runtime.h>
#include <stdint.h>

// Problem constants
constexpr int B_ = 8, N_ = 4096, E_ = 2048, C_ = 128;
constexpr int CN = 144;   // 128 channels + 1 ones-col + 15 pad
constexpr int KT = 32;    // K per MFMA tile-step
constexpr int MT = 64;    // M tile per block (4 waves x 16 rows)
constexpr int LROW = 40;  // padded LDS row length in bf16 elems (16B-aligned, even bank spread)

typedef short bf16x8 __attribute__((ext_vector_type(8)));
typedef float f32x4  __attribute__((ext_vector_type(4)));

__device__ inline uint16_t bf16_rne(float f) {
    uint32_t u = __builtin_bit_cast(uint32_t, f);
    return (uint16_t)((u + 0x7FFFu + ((u >> 16) & 1u)) >> 16);
}
__device__ inline uint16_t bf16_trunc(float f) {   // exact for 0.0 / 1.0 (H entries)
    return (uint16_t)(__builtin_bit_cast(uint32_t, f) >> 16);
}

constexpr size_t PE_ELEMS = (size_t)B_ * E_ * CN;  // fp32 v2e partials (col 128 = s_e)
constexpr size_t DN_ELEMS = (size_t)B_ * N_;       // fp32 node-degree partials
constexpr size_t WT_ELEMS = (size_t)CN * C_;       // bf16 W^T padded

// ---------------------------------------------------------------------------
// prep: zero Pe; WTb = bf16(W^T) padded to 144 rows; xwbT ones rows 128..143
// ---------------------------------------------------------------------------
__global__ void prep_kernel(const float* __restrict__ W, float* __restrict__ Pe,
                            uint16_t* __restrict__ WTb, uint32_t* __restrict__ xwbT32) {
    const int NZ4 = (int)(PE_ELEMS / 4);           // 589824 float4 zeros
    const int NW  = (int)WT_ELEMS;                 // 18432
    const int NX  = B_ * 16 * (N_ / 2);            // 262144 dwords (ones rows)
    int stride = gridDim.x * blockDim.x;
    for (int i = blockIdx.x * blockDim.x + threadIdx.x; i < NZ4 + NW + NX; i += stride) {
        if (i < NZ4) {
            ((float4*)Pe)[i] = make_float4(0.f, 0.f, 0.f, 0.f);
        } else if (i < NZ4 + NW) {
            int j = i - NZ4; int c = j >> 7, k = j & 127;
            WTb[j] = bf16_rne((c < C_) ? W[k * C_ + c] : 0.f);
        } else {
            int j = i - NZ4 - NW;
            int b = j >> 15, rr = j & 32767;
            int r = rr >> 11, n2 = rr & 2047;
            xwbT32[((size_t)b * CN + (C_ + r)) * (N_ / 2) + n2] = (r == 0) ? 0x3F803F80u : 0u;
        }
    }
}

// ---------------------------------------------------------------------------
// MFMA GEMM with register-level pipelining + split-K.
//  MODE 0 (fc) : A = x [32768 x 128] NT, B = WTb,  direct bf16 C^T store + bias
//  MODE 1 (v2e): A = H^T (k*E_+m),      B = xwbT, atomicAdd fp32 -> Pe[b][e][144]
//  MODE 2 (e2v): A = H [4096 x 2048] NT, B = ebfT, atomicAdd fp32 -> out[b][n][128], Dn
// Block: 256 thr = 4 waves, M-tile 64 (16 rows/wave), 9 col tiles (144 cols).
// ---------------------------------------------------------------------------
template <int MODE>
__global__ __launch_bounds__(256, 4)
void gemm_k(const float* __restrict__ Ab, const uint16_t* __restrict__ Btb,
            const float* __restrict__ bias, uint16_t* __restrict__ outT,
            float* __restrict__ Pout, float* __restrict__ Dn) {
    constexpr bool ATR = (MODE == 1);
    constexpr int  K   = (MODE == 0) ? C_ : (MODE == 1) ? N_ : E_;
    constexpr int  M   = (MODE == 1) ? E_ : N_;
    constexpr int  LDA = (MODE == 0) ? C_ : E_;
    constexpr size_t ABS = (MODE == 0) ? (size_t)N_ * C_ : (size_t)N_ * E_;
    constexpr int  LDB = K;
    constexpr size_t BBS = (MODE == 0) ? 0 : (size_t)CN * K;
    constexpr int  KSPLIT = (MODE == 0) ? 1 : (MODE == 1) ? 4 : 2;
    constexpr int  S   = K / KSPLIT / KT;          // 4 / 32 / 32
    constexpr int  NMT = M / MT;                   // 64 / 32 / 64
    constexpr int  NSEG = CN * KT / 8;             // 576 16B segments of B tile

    __shared__ uint16_t Alds[MT * LROW];           // [m][k], padded rows
    __shared__ uint16_t Blds[CN * LROW];           // [c][k], padded rows

    const int t     = threadIdx.x;
    const int batch = blockIdx.x & 7;              // consecutive blocks -> XCD spread; B stays in its L2
    const int rest  = blockIdx.x >> 3;
    const int mtile = rest % NMT;
    const int ksp   = rest / NMT;
    const int m0    = mtile * MT;
    const int kbase = ksp * (K / KSPLIT);
    const int lane  = t & 63, wave = t >> 6;
    const int l15   = lane & 15, quad = lane >> 4;

    const float*    Ap = Ab + (size_t)batch * ABS;
    const uint16_t* Bp = Btb + (size_t)batch * BBS;

    f32x4 acc[9];
#pragma unroll
    for (int j = 0; j < 9; ++j) acc[j] = (f32x4){0.f, 0.f, 0.f, 0.f};

    int am, ak;
    if (ATR) { am = t & 63;  ak = (t >> 6) * 8; }  // gather-transpose: 8 k's, one m
    else     { am = t >> 2;  ak = (t & 3) * 8;  }  // row-major: one m, 8 consecutive k

    auto loadA = [&](int k0, float* dst) {
        if (ATR) {
            const float* ap = Ap + (size_t)(k0 + ak) * LDA + (m0 + am);
#pragma unroll
            for (int i = 0; i < 8; ++i) dst[i] = ap[(size_t)i * LDA];
        } else {
            const float* ap = Ap + (size_t)(m0 + am) * LDA + (k0 + ak);
            const float4 f0 = *(const float4*)ap;
            const float4 f1 = *(const float4*)(ap + 4);
            dst[0] = f0.x; dst[1] = f0.y; dst[2] = f0.z; dst[3] = f0.w;
            dst[4] = f1.x; dst[5] = f1.y; dst[6] = f1.z; dst[7] = f1.w;
        }
    };
    auto loadB = [&](int k0, uint4* dst) {
#pragma unroll
        for (int jj = 0; jj < 3; ++jj) {
            int seg = t + 256 * jj;
            if (seg < NSEG) {
                int c = seg >> 2, kk = (seg & 3) * 8;
                dst[jj] = *(const uint4*)(Bp + (size_t)c * LDB + k0 + kk);
            }
        }
    };

    float av[8]; uint4 bv[3];
    loadA(kbase, av); loadB(kbase, bv);

#pragma unroll 1
    for (int s = 0; s < S; ++s) {
        float av2[8]; uint4 bv2[3];
        const bool more = (s + 1 < S);
        if (more) {                                 // issue next-iter loads EARLY:
            loadA(kbase + (s + 1) * KT, av2);       // full iteration of latency slack
            loadB(kbase + (s + 1) * KT, bv2);
        }
        __syncthreads();                            // fragment reads of iter s-1 done
        uint32_t p0, p1, p2, p3;
        if (MODE == 0) {
            p0 = (uint32_t)bf16_rne(av[0]) | ((uint32_t)bf16_rne(av[1]) << 16);
            p1 = (uint32_t)bf16_rne(av[2]) | ((uint32_t)bf16_rne(av[3]) << 16);
            p2 = (uint32_t)bf16_rne(av[4]) | ((uint32_t)bf16_rne(av[5]) << 16);
            p3 = (uint32_t)bf16_rne(av[6]) | ((uint32_t)bf16_rne(av[7]) << 16);
        } else {
            p0 = (uint32_t)bf16_trunc(av[0]) | ((uint32_t)bf16_trunc(av[1]) << 16);
            p1 = (uint32_t)bf16_trunc(av[2]) | ((uint32_t)bf16_trunc(av[3]) << 16);
            p2 = (uint32_t)bf16_trunc(av[4]) | ((uint32_t)bf16_trunc(av[5]) << 16);
            p3 = (uint32_t)bf16_trunc(av[6]) | ((uint32_t)bf16_trunc(av[7]) << 16);
        }
        *(uint4*)&Alds[am * LROW + ak] = make_uint4(p0, p1, p2, p3);
#pragma unroll
        for (int jj = 0; jj < 3; ++jj) {
            int seg = t + 256 * jj;
            if (seg < NSEG) *(uint4*)&Blds[(seg >> 2) * LROW + (seg & 3) * 8] = bv[jj];
        }
        __syncthreads();
        bf16x8 af = *(const bf16x8*)&Alds[(wave * 16 + l15) * LROW + quad * 8];
#pragma unroll
        for (int j = 0; j < 9; ++j) {
            bf16x8 bf = *(const bf16x8*)&Blds[(j * 16 + l15) * LROW + quad * 8];
            acc[j] = __builtin_amdgcn_mfma_f32_16x16x32_bf16(af, bf, acc[j], 0, 0, 0);
        }
        if (more) {
#pragma unroll
            for (int i = 0; i < 8; ++i) av[i] = av2[i];
#pragma unroll
            for (int jj = 0; jj < 3; ++jj) bv[jj] = bv2[jj];
        }
    }

    // ---- epilogue ----
    const int row = m0 + wave * 16 + quad * 4;
    if constexpr (MODE == 0) {
#pragma unroll
        for (int j = 0; j < 8; ++j) {
            int c = j * 16 + l15;
            float add = bias[c];
            uint32_t q0 = (uint32_t)bf16_rne(acc[j][0] + add) | ((uint32_t)bf16_rne(acc[j][1] + add) << 16);
            uint32_t q1 = (uint32_t)bf16_rne(acc[j][2] + add) | ((uint32_t)bf16_rne(acc[j][3] + add) << 16);
            uint16_t* op = outT + ((size_t)batch * CN + c) * N_ + row;
            *(uint2*)op = make_uint2(q0, q1);
        }
    } else if constexpr (MODE == 1) {
        float* Pp = Pout + ((size_t)batch * E_ + row) * CN;
#pragma unroll
        for (int j = 0; j < 8; ++j) {
            int c = j * 16 + l15;
#pragma unroll
            for (int r = 0; r < 4; ++r) atomicAdd(&Pp[(size_t)r * CN + c], acc[j][r]);
        }
        if (l15 == 0) {
#pragma unroll
            for (int r = 0; r < 4; ++r) atomicAdd(&Pp[(size_t)r * CN + C_], acc[8][r]);
        }
    } else {
        float* Op = Pout + ((size_t)batch * N_ + row) * C_;
#pragma unroll
        for (int j = 0; j < 8; ++j) {
            int c = j * 16 + l15;
#pragma unroll
            for (int r = 0; r < 4; ++r) atomicAdd(&Op[(size_t)r * C_ + c], acc[j][r]);
        }
        if (l15 == 0) {
#pragma unroll
            for (int r = 0; r < 4; ++r) atomicAdd(&Dn[(size_t)batch * N_ + row + r], acc[8][r]);
        }
    }
}

// ---------------------------------------------------------------------------
// fin_e: Pe[b][e][144] -> ebfT[b][c][e] bf16 with /s_e; ones row 128; zero rows
// 129..143. Also zeroes d_out + Dn for e2v's atomic accumulation.
// Grid: 8 * 32 blocks x 256 thr (64 e per block).
// ---------------------------------------------------------------------------
__global__ void fin_e_kernel(const float* __restrict__ Pe, uint16_t* __restrict__ ebfT,
                             float4* __restrict__ outZ, float* __restrict__ DnZ) {
    __shared__ float T[144 * 65];
    const int t  = threadIdx.x;
    const int b  = blockIdx.x >> 5;
    const int e0 = (blockIdx.x & 31) * 64;
#pragma unroll
    for (int i = 0; i < 9; ++i) {
        int seg = i * 256 + t;
        if (seg < 2304) {
            int row = seg / 36, c4 = seg % 36;
            float4 v = *(const float4*)&Pe[((size_t)b * E_ + e0 + row) * CN + c4 * 4];
            T[(c4 * 4 + 0) * 65 + row] = v.x;
            T[(c4 * 4 + 1) * 65 + row] = v.y;
            T[(c4 * 4 + 2) * 65 + row] = v.z;
            T[(c4 * 4 + 3) * 65 + row] = v.w;
        }
    }
    __syncthreads();
    const int e = t & 63, w = t >> 6;
    float cnt = T[128 * 65 + e];
    float rcp = (cnt > 0.f) ? 1.f / cnt : 0.f;
    uint16_t* op = ebfT + (size_t)b * CN * E_ + e0 + e;
#pragma unroll 4
    for (int cc = 0; cc < 32; ++cc) {
        int c = w * 32 + cc;
        op[(size_t)c * E_] = bf16_rne(T[c * 65 + e] * rcp);
    }
#pragma unroll
    for (int i = 0; i < 4; ++i) {
        int c = C_ + w * 4 + i;
        op[(size_t)c * E_] = (c == C_) ? (uint16_t)0x3F80 : (uint16_t)0;
    }
    // zero the e2v accumulation targets
    const int nth = gridDim.x * blockDim.x;          // 65536
    const int gid = blockIdx.x * blockDim.x + t;
    const int NO4 = B_ * N_ * C_ / 4;                // 1048576
    for (int i = gid; i < NO4; i += nth) outZ[i] = make_float4(0.f, 0.f, 0.f, 0.f);
    const int ND = (int)DN_ELEMS;                    // 32768
    for (int i = gid; i < ND; i += nth) DnZ[i] = 0.f;
}

// ---------------------------------------------------------------------------
// fin_v: out[b][n][c] *= rcp(Dn[b][n]) in place.
// ---------------------------------------------------------------------------
__global__ void fin_v_kernel(float* __restrict__ out, const float* __restrict__ Dn) {
    const int NO4 = B_ * N_ * C_ / 4;
    int stride = gridDim.x * blockDim.x;
    for (int i = blockIdx.x * blockDim.x + threadIdx.x; i < NO4; i += stride) {
        int ng = i >> 5;
        float cnt = Dn[ng];
        float rcp = (cnt > 0.f) ? 1.f / cnt : 0.f;
        float4 v = ((float4*)out)[i];
        v.x *= rcp; v.y *= rcp; v.z *= rcp; v.w *= rcp;
        ((float4*)out)[i] = v;
    }
}

// ---------------------------------------------------------------------------
extern "C" void kernel_launch(void* const* d_in, const int* in_sizes, int n_in,
                              void* d_out, int out_size, void* d_ws, size_t ws_size,
                              hipStream_t stream) {
    const float* x    = (const float*)d_in[0];   // [8,4096,128]
    const float* H    = (const float*)d_in[1];   // [8,4096,2048]
    const float* W    = (const float*)d_in[2];   // [128,128]
    const float* bias = (const float*)d_in[3];   // [128]
    float* out = (float*)d_out;                  // [8,4096,128]

    // ws layout (~14.3 MB): Pe | Dn | WTb | ebfT ; xwbT lives in d_out (dead after v2e)
    float*    Pe   = (float*)d_ws;
    float*    Dn   = Pe + PE_ELEMS;
    uint16_t* WTb  = (uint16_t*)(Dn + DN_ELEMS);
    uint16_t* ebfT = WTb + WT_ELEMS;
    uint16_t* xwbT = (uint16_t*)d_out;

    prep_kernel<<<dim3(1024), dim3(256), 0, stream>>>(W, Pe, WTb, (uint32_t*)xwbT);
    gemm_k<0><<<dim3(8 * (N_ / MT)),     dim3(256), 0, stream>>>(x, WTb, bias, xwbT, nullptr, nullptr);
    gemm_k<1><<<dim3(8 * (E_ / MT) * 4), dim3(256), 0, stream>>>(H, xwbT, nullptr, nullptr, Pe, nullptr);
    fin_e_kernel<<<dim3(8 * (E_ / 64)),  dim3(256), 0, stream>>>(Pe, ebfT, (float4*)out, Dn);
    gemm_k<2><<<dim3(8 * (N_ / MT) * 2), dim3(256), 0, stream>>>(H, ebfT, nullptr, nullptr, out, Dn);
    fin_v_kernel<<<dim3(1024), dim3(256), 0, stream>>>(out, Dn);
}

// Round 3
// 693.273 us; speedup vs baseline: 1.3607x; 1.3607x over previous
//
#include <hip/hip_runtime.h>
#include <stdint.h>

// Problem constants
constexpr int B_ = 8, N_ = 4096, E_ = 2048, C_ = 128;
constexpr int CN = 144;   // 128 channels + 1 ones-col + 15 pad
constexpr int KT = 32;    // K per MFMA tile-step
constexpr int MT = 64;    // M tile per block (4 waves x 16 rows)
constexpr int LROW = 40;  // padded LDS row (bf16 elems): 20-bank stride -> conflict-free b128

typedef short bf16x8 __attribute__((ext_vector_type(8)));
typedef float f32x4  __attribute__((ext_vector_type(4)));

__device__ inline uint16_t bf16_rne(float f) {
    uint32_t u = __builtin_bit_cast(uint32_t, f);
    return (uint16_t)((u + 0x7FFFu + ((u >> 16) & 1u)) >> 16);
}
__device__ inline uint16_t bf16_trunc(float f) {   // exact for 0.0 / 1.0 (H entries)
    return (uint16_t)(__builtin_bit_cast(uint32_t, f) >> 16);
}

constexpr size_t PE1   = (size_t)B_ * E_ * CN;   // one v2e partial copy (floats)
constexpr size_t DN1   = (size_t)B_ * N_;        // one node-degree copy (floats)
constexpr size_t WT_E  = (size_t)CN * C_;        // bf16 W^T padded (elems)
constexpr size_t EBF_E = (size_t)B_ * CN * E_;   // ebfT elems (== PE1)

// ---------------------------------------------------------------------------
// prep: (tier C only) zero Pe; WTb = bf16(W^T) padded; xwbT ones rows 128..143
// ---------------------------------------------------------------------------
template <bool ZPE>
__global__ void prep_kernel(const float* __restrict__ W, float* __restrict__ Pe,
                            uint16_t* __restrict__ WTb, uint32_t* __restrict__ xwbT32) {
    const int NZ4 = ZPE ? (int)(PE1 / 4) : 0;
    const int NW  = (int)WT_E;                 // 18432
    const int NX  = B_ * 16 * (N_ / 2);        // 262144 dwords (ones rows of xwbT)
    int stride = gridDim.x * blockDim.x;
    for (int i = blockIdx.x * blockDim.x + threadIdx.x; i < NZ4 + NW + NX; i += stride) {
        if (ZPE && i < NZ4) {
            ((float4*)Pe)[i] = make_float4(0.f, 0.f, 0.f, 0.f);
        } else if (i < NZ4 + NW) {
            int j = i - NZ4; int c = j >> 7, k = j & 127;
            WTb[j] = bf16_rne((c < C_) ? W[k * C_ + c] : 0.f);
        } else {
            int j = i - NZ4 - NW;
            int b = j >> 15, rr = j & 32767;
            int r = rr >> 11, n2 = rr & 2047;
            xwbT32[((size_t)b * CN + (C_ + r)) * (N_ / 2) + n2] = (r == 0) ? 0x3F803F80u : 0u;
        }
    }
}

// ---------------------------------------------------------------------------
// MFMA GEMM, split-K into disjoint partial buffers (no atomics in tiers A/B).
//  MODE 0 (fc) : A = x NT,  B = WTb,  bf16 C^T store + bias -> xwbT
//  MODE 1 (v2e): A = H^T,   B = xwbT, fp32 plain store -> P0[ksp][b][e][144]
//  MODE 2 (e2v): A = H NT,  B = ebfT, fp32 plain store -> ksp0: out, ksp1: P1; Dn0/Dn1
// 256 thr = 4 waves, M-tile 64, 9 col tiles. Col 128 = ones-col (s_e / d_n).
// Register pipeline: A double-buffered ~1.8 iters ahead, B 1 iter ahead (L2-hit).
// ---------------------------------------------------------------------------
template <int MODE, int KSP, bool ATOM>
__global__ __launch_bounds__(256, 3)
void gemm_k(const float* __restrict__ Ab, const uint16_t* __restrict__ Btb,
            const float* __restrict__ bias, uint16_t* __restrict__ outT,
            float* __restrict__ P0, float* __restrict__ P1,
            float* __restrict__ Dn0, float* __restrict__ Dn1) {
    constexpr bool ATR = (MODE == 1);
    constexpr int  K   = (MODE == 0) ? C_ : (MODE == 1) ? N_ : E_;
    constexpr int  M   = (MODE == 1) ? E_ : N_;
    constexpr int  LDA = (MODE == 0) ? C_ : E_;
    constexpr size_t ABS = (MODE == 0) ? (size_t)N_ * C_ : (size_t)N_ * E_;
    constexpr int  LDB = K;
    constexpr size_t BBS = (MODE == 0) ? 0 : (size_t)CN * K;
    constexpr int  S   = K / KSP / KT;
    constexpr int  NMT = M / MT;
    constexpr int  NSEG = CN * KT / 8;             // 576 16B segments of B tile

    __shared__ uint16_t Alds[MT * LROW];
    __shared__ uint16_t Blds[CN * LROW];

    const int t     = threadIdx.x;
    const int batch = blockIdx.x & 7;              // consecutive blocks -> XCD spread
    const int rest  = blockIdx.x >> 3;
    const int mtile = rest % NMT;
    const int ksp   = rest / NMT;
    const int m0    = mtile * MT;
    const int kb    = ksp * (K / KSP);
    const int lane  = t & 63, wave = t >> 6;
    const int l15   = lane & 15, quad = lane >> 4;

    const float*    Ap = Ab + (size_t)batch * ABS;
    const uint16_t* Bp = Btb + (size_t)batch * BBS;

    f32x4 acc[9];
#pragma unroll
    for (int j = 0; j < 9; ++j) acc[j] = (f32x4){0.f, 0.f, 0.f, 0.f};

    int am, ak;
    if (ATR) { am = t & 63;  ak = (t >> 6) * 8; }  // 8 strided-by-LDA k's, coalesced over m
    else     { am = t >> 2;  ak = (t & 3) * 8;  }  // 8 consecutive k, coalesced over m groups

    auto loadA = [&](int k0, float (&dst)[8]) {
        if (ATR) {
            const float* ap = Ap + (size_t)(k0 + ak) * LDA + (m0 + am);
#pragma unroll
            for (int i = 0; i < 8; ++i) dst[i] = ap[(size_t)i * LDA];
        } else {
            const float* ap = Ap + (size_t)(m0 + am) * LDA + (k0 + ak);
            const float4 f0 = *(const float4*)ap;
            const float4 f1 = *(const float4*)(ap + 4);
            dst[0] = f0.x; dst[1] = f0.y; dst[2] = f0.z; dst[3] = f0.w;
            dst[4] = f1.x; dst[5] = f1.y; dst[6] = f1.z; dst[7] = f1.w;
        }
    };
    auto loadB = [&](int k0, uint4 (&dst)[3]) {
#pragma unroll
        for (int jj = 0; jj < 3; ++jj) {
            int seg = t + 256 * jj;
            if (seg < NSEG) {
                int c = seg >> 2, kk = (seg & 3) * 8;
                dst[jj] = *(const uint4*)(Bp + (size_t)c * LDB + k0 + kk);
            }
        }
    };

    auto do_iter = [&](int s, float (&avC)[8], uint4 (&bvC)[3], uint4 (&bvN)[3]) {
        __syncthreads();                            // prev iter's fragment reads done
        uint32_t p0, p1, p2, p3;
        if (MODE == 0) {
            p0 = (uint32_t)bf16_rne(avC[0]) | ((uint32_t)bf16_rne(avC[1]) << 16);
            p1 = (uint32_t)bf16_rne(avC[2]) | ((uint32_t)bf16_rne(avC[3]) << 16);
            p2 = (uint32_t)bf16_rne(avC[4]) | ((uint32_t)bf16_rne(avC[5]) << 16);
            p3 = (uint32_t)bf16_rne(avC[6]) | ((uint32_t)bf16_rne(avC[7]) << 16);
        } else {
            p0 = (uint32_t)bf16_trunc(avC[0]) | ((uint32_t)bf16_trunc(avC[1]) << 16);
            p1 = (uint32_t)bf16_trunc(avC[2]) | ((uint32_t)bf16_trunc(avC[3]) << 16);
            p2 = (uint32_t)bf16_trunc(avC[4]) | ((uint32_t)bf16_trunc(avC[5]) << 16);
            p3 = (uint32_t)bf16_trunc(avC[6]) | ((uint32_t)bf16_trunc(avC[7]) << 16);
        }
        *(uint4*)&Alds[am * LROW + ak] = make_uint4(p0, p1, p2, p3);
#pragma unroll
        for (int jj = 0; jj < 3; ++jj) {
            int seg = t + 256 * jj;
            if (seg < NSEG) *(uint4*)&Blds[(seg >> 2) * LROW + (seg & 3) * 8] = bvC[jj];
        }
        if (s + 2 < S) loadA(kb + (s + 2) * KT, avC);   // avC regs free after store
        if (s + 1 < S) loadB(kb + (s + 1) * KT, bvN);
        __syncthreads();
        bf16x8 af = *(const bf16x8*)&Alds[(wave * 16 + l15) * LROW + quad * 8];
#pragma unroll
        for (int j = 0; j < 9; ++j) {
            bf16x8 bf = *(const bf16x8*)&Blds[(j * 16 + l15) * LROW + quad * 8];
            acc[j] = __builtin_amdgcn_mfma_f32_16x16x32_bf16(af, bf, acc[j], 0, 0, 0);
        }
    };

    float avA[8], avB[8]; uint4 bvA[3], bvB[3];
    loadA(kb, avA);
    if (S > 1) loadA(kb + KT, avB);
    loadB(kb, bvA);
#pragma unroll 1
    for (int s = 0; s < S; s += 2) {
        do_iter(s,     avA, bvA, bvB);
        do_iter(s + 1, avB, bvB, bvA);
    }

    // ---- epilogue ----
    const int row = m0 + wave * 16 + quad * 4;
    if constexpr (MODE == 0) {
#pragma unroll
        for (int j = 0; j < 8; ++j) {
            int c = j * 16 + l15;
            float add = bias[c];
            uint32_t q0 = (uint32_t)bf16_rne(acc[j][0] + add) | ((uint32_t)bf16_rne(acc[j][1] + add) << 16);
            uint32_t q1 = (uint32_t)bf16_rne(acc[j][2] + add) | ((uint32_t)bf16_rne(acc[j][3] + add) << 16);
            uint16_t* op = outT + ((size_t)batch * CN + c) * N_ + row;
            *(uint2*)op = make_uint2(q0, q1);
        }
    } else if constexpr (MODE == 1) {
        float* Pp = P0 + (ATOM ? 0 : (size_t)ksp * PE1) + ((size_t)batch * E_ + row) * CN;
#pragma unroll
        for (int j = 0; j < 8; ++j) {
            int c = j * 16 + l15;
#pragma unroll
            for (int r = 0; r < 4; ++r) {
                if (ATOM) atomicAdd(&Pp[(size_t)r * CN + c], acc[j][r]);
                else      Pp[(size_t)r * CN + c] = acc[j][r];
            }
        }
        if (l15 == 0) {
#pragma unroll
            for (int r = 0; r < 4; ++r) {
                if (ATOM) atomicAdd(&Pp[(size_t)r * CN + C_], acc[8][r]);
                else      Pp[(size_t)r * CN + C_] = acc[8][r];
            }
        }
    } else {
        float* Op = (ATOM || ksp == 0 ? P0 : P1) + ((size_t)batch * N_ + row) * C_;
        float* Dp = (ATOM || ksp == 0 ? Dn0 : Dn1) + (size_t)batch * N_ + row;
#pragma unroll
        for (int j = 0; j < 8; ++j) {
            int c = j * 16 + l15;
#pragma unroll
            for (int r = 0; r < 4; ++r) {
                if (ATOM) atomicAdd(&Op[(size_t)r * C_ + c], acc[j][r]);
                else      Op[(size_t)r * C_ + c] = acc[j][r];
            }
        }
        if (l15 == 0) {
#pragma unroll
            for (int r = 0; r < 4; ++r) {
                if (ATOM) atomicAdd(&Dp[r], acc[8][r]);
                else      Dp[r] = acc[8][r];
            }
        }
    }
}

// ---------------------------------------------------------------------------
// fin_e: sum NP partial copies of Pe -> ebfT[b][c][e] bf16 with /s_e; row 128
// ones; rows 129..143 zero. ZOUT (atomic tier): also zero out + Dn0 for e2v.
// ---------------------------------------------------------------------------
template <int NP, bool ZOUT>
__global__ void fin_e_kernel(const float* __restrict__ Pe, uint16_t* __restrict__ ebfT,
                             float4* __restrict__ outZ, float* __restrict__ DnZ) {
    __shared__ float T[144 * 65];
    const int t  = threadIdx.x;
    const int b  = blockIdx.x >> 5;
    const int e0 = (blockIdx.x & 31) * 64;
#pragma unroll
    for (int i = 0; i < 9; ++i) {
        int seg = i * 256 + t;
        if (seg < 2304) {
            int row = seg / 36, c4 = seg % 36;
            size_t off = ((size_t)b * E_ + e0 + row) * CN + c4 * 4;
            float4 v = *(const float4*)&Pe[off];
#pragma unroll
            for (int p = 1; p < NP; ++p) {
                float4 u = *(const float4*)&Pe[(size_t)p * PE1 + off];
                v.x += u.x; v.y += u.y; v.z += u.z; v.w += u.w;
            }
            T[(c4 * 4 + 0) * 65 + row] = v.x;
            T[(c4 * 4 + 1) * 65 + row] = v.y;
            T[(c4 * 4 + 2) * 65 + row] = v.z;
            T[(c4 * 4 + 3) * 65 + row] = v.w;
        }
    }
    __syncthreads();
    const int e = t & 63, w = t >> 6;
    float cnt = T[128 * 65 + e];
    float rcp = (cnt > 0.f) ? 1.f / cnt : 0.f;
    uint16_t* op = ebfT + (size_t)b * CN * E_ + e0 + e;
#pragma unroll 4
    for (int cc = 0; cc < 32; ++cc) {
        int c = w * 32 + cc;
        op[(size_t)c * E_] = bf16_rne(T[c * 65 + e] * rcp);
    }
#pragma unroll
    for (int i = 0; i < 4; ++i) {
        int c = C_ + w * 4 + i;
        op[(size_t)c * E_] = (c == C_) ? (uint16_t)0x3F80 : (uint16_t)0;
    }
    if constexpr (ZOUT) {
        const int nth = gridDim.x * blockDim.x;
        const int gid = blockIdx.x * blockDim.x + t;
        const int NO4 = B_ * N_ * C_ / 4;
        for (int i = gid; i < NO4; i += nth) outZ[i] = make_float4(0.f, 0.f, 0.f, 0.f);
        const int ND = (int)DN1;
        for (int i = gid; i < ND; i += nth) DnZ[i] = 0.f;
    }
}

// ---------------------------------------------------------------------------
// fin_v: out = (out [+ Po1]) * rcp(Dn0 [+ Dn1]) in place.
// ---------------------------------------------------------------------------
template <int NPV>
__global__ void fin_v_kernel(float* __restrict__ out, const float* __restrict__ Po1,
                             const float* __restrict__ Dn0, const float* __restrict__ Dn1) {
    const int NO4 = B_ * N_ * C_ / 4;
    int stride = gridDim.x * blockDim.x;
    for (int i = blockIdx.x * blockDim.x + threadIdx.x; i < NO4; i += stride) {
        int ng = i >> 5;
        float cnt = Dn0[ng] + (NPV == 2 ? Dn1[ng] : 0.f);
        float rcp = (cnt > 0.f) ? 1.f / cnt : 0.f;
        float4 v = ((float4*)out)[i];
        if (NPV == 2) {
            float4 u = ((const float4*)Po1)[i];
            v.x += u.x; v.y += u.y; v.z += u.z; v.w += u.w;
        }
        v.x *= rcp; v.y *= rcp; v.z *= rcp; v.w *= rcp;
        ((float4*)out)[i] = v;
    }
}

// ---------------------------------------------------------------------------
extern "C" void kernel_launch(void* const* d_in, const int* in_sizes, int n_in,
                              void* d_out, int out_size, void* d_ws, size_t ws_size,
                              hipStream_t stream) {
    const float* x    = (const float*)d_in[0];   // [8,4096,128]
    const float* H    = (const float*)d_in[1];   // [8,4096,2048]
    const float* W    = (const float*)d_in[2];   // [128,128]
    const float* bias = (const float*)d_in[3];   // [128]
    float* out = (float*)d_out;                  // [8,4096,128]

    // ws tiers (constant per process -> graph-safe):
    //  A (>=43MB): v2e 4-way split-K partials, e2v 2-way, zero atomics
    //  B (>=24MB): v2e 2-way split-K partials, e2v 2-way, zero atomics
    //  C        : round-2-style atomic fallback (proven correct, slower)
    const size_t needA = (4 * PE1 + 2 * DN1) * 4 + (WT_E + EBF_E) * 2;
    const size_t needB = (2 * PE1 + 2 * DN1) * 4 + (WT_E + EBF_E) * 2;
    const int ncopy = (ws_size >= needA) ? 4 : (ws_size >= needB) ? 2 : 1;

    float*    Pe   = (float*)d_ws;               // [ncopy][B][E][CN]
    float*    Dn0  = Pe + (size_t)ncopy * PE1;
    float*    Dn1  = Dn0 + DN1;
    uint16_t* WTb  = (uint16_t*)(Dn1 + DN1);
    uint16_t* ebfT = WTb + WT_E;
    float*    Po1  = Pe;                         // e2v ksp1 partial reuses Pe region
    uint16_t* xwbT = (uint16_t*)d_out;           // dead scratch until e2v overwrites

    if (ncopy == 4) {
        prep_kernel<false><<<dim3(512), dim3(256), 0, stream>>>(W, Pe, WTb, (uint32_t*)xwbT);
        gemm_k<0, 1, false><<<dim3(512),  dim3(256), 0, stream>>>(x, WTb, bias, xwbT, nullptr, nullptr, nullptr, nullptr);
        gemm_k<1, 4, false><<<dim3(1024), dim3(256), 0, stream>>>(H, xwbT, nullptr, nullptr, Pe, nullptr, nullptr, nullptr);
        fin_e_kernel<4, false><<<dim3(256), dim3(256), 0, stream>>>(Pe, ebfT, nullptr, nullptr);
        gemm_k<2, 2, false><<<dim3(1024), dim3(256), 0, stream>>>(H, ebfT, nullptr, nullptr, out, Po1, Dn0, Dn1);
        fin_v_kernel<2><<<dim3(2048), dim3(256), 0, stream>>>(out, Po1, Dn0, Dn1);
    } else if (ncopy == 2) {
        prep_kernel<false><<<dim3(512), dim3(256), 0, stream>>>(W, Pe, WTb, (uint32_t*)xwbT);
        gemm_k<0, 1, false><<<dim3(512),  dim3(256), 0, stream>>>(x, WTb, bias, xwbT, nullptr, nullptr, nullptr, nullptr);
        gemm_k<1, 2, false><<<dim3(512),  dim3(256), 0, stream>>>(H, xwbT, nullptr, nullptr, Pe, nullptr, nullptr, nullptr);
        fin_e_kernel<2, false><<<dim3(256), dim3(256), 0, stream>>>(Pe, ebfT, nullptr, nullptr);
        gemm_k<2, 2, false><<<dim3(1024), dim3(256), 0, stream>>>(H, ebfT, nullptr, nullptr, out, Po1, Dn0, Dn1);
        fin_v_kernel<2><<<dim3(2048), dim3(256), 0, stream>>>(out, Po1, Dn0, Dn1);
    } else {
        prep_kernel<true><<<dim3(1024), dim3(256), 0, stream>>>(W, Pe, WTb, (uint32_t*)xwbT);
        gemm_k<0, 1, false><<<dim3(512),  dim3(256), 0, stream>>>(x, WTb, bias, xwbT, nullptr, nullptr, nullptr, nullptr);
        gemm_k<1, 4, true><<<dim3(1024),  dim3(256), 0, stream>>>(H, xwbT, nullptr, nullptr, Pe, nullptr, nullptr, nullptr);
        fin_e_kernel<1, true><<<dim3(256), dim3(256), 0, stream>>>(Pe, ebfT, (float4*)out, Dn0);
        gemm_k<2, 2, true><<<dim3(1024),  dim3(256), 0, stream>>>(H, ebfT, nullptr, nullptr, out, nullptr, Dn0, nullptr);
        fin_v_kernel<1><<<dim3(2048), dim3(256), 0, stream>>>(out, nullptr, Dn0, nullptr);
    }
}